// Round 2
// baseline (746.650 us; speedup 1.0000x reference)
//
#include <hip/hip_runtime.h>
#include <stdint.h>

#define B_  256
#define T_  512
#define H_  128
#define NSW 6

typedef __bf16 bf2_t  __attribute__((ext_vector_type(2)));
typedef int    i32x4  __attribute__((ext_vector_type(4)));
typedef float  f32x4  __attribute__((ext_vector_type(4)));

// float -> bf16 round-to-nearest-even
__device__ __forceinline__ unsigned short f2bf(float f){
  unsigned u = __float_as_uint(f);
  unsigned r = u + 0x7FFFu + ((u >> 16) & 1u);
  return (unsigned short)(r >> 16);
}
__device__ __forceinline__ unsigned pack2(float a, float b){
  return (unsigned)f2bf(a) | ((unsigned)f2bf(b) << 16);
}
__device__ __forceinline__ float dot2bf(unsigned wpair, unsigned hpair, float acc){
  return __builtin_amdgcn_fdot2_f32_bf16(__builtin_bit_cast(bf2_t, wpair),
                                         __builtin_bit_cast(bf2_t, hpair), acc, false);
}
__device__ __forceinline__ void lds_barrier(){
  asm volatile("s_waitcnt lgkmcnt(0)\ns_barrier" ::: "memory");
}

// Per-row symmetric int8 quantization into MFMA A-fragment order.
// uint2 idx = ((gs*2+hf)*16 + rg*4 + kc)*64 + q*16 + r holds int8 of
//   W[gs][row = hf*64+rg*16+r][k = kc*32 + q*8 + 0..7]  (byte e = k offset e)
// scales[gs*128+row] = rowmax / (127*127)  (dequant factor incl. h scale 1/127)
__global__ __launch_bounds__(256) void pack_weights_i8(const float* __restrict__ Wr,
                                                       const float* __restrict__ Wz,
                                                       const float* __restrict__ Wn,
                                                       uint2* __restrict__ dst,
                                                       float* __restrict__ scales){
  int idx = blockIdx.x * 256 + threadIdx.x;     // (gs, row)
  if (idx >= 18 * 128) return;
  int row = idx & 127;
  int gs  = idx >> 7;
  int s = gs % NSW, g = gs / NSW;
  const float* W = (g == 0) ? Wr : (g == 1) ? Wz : Wn;
  const float* src = W + (size_t)s * (H_*H_) + (size_t)row * H_;
  float amax = 0.f;
  for (int j = 0; j < H_; ++j) amax = fmaxf(amax, fabsf(src[j]));
  amax = fmaxf(amax, 1e-20f);
  float inv = 127.f / amax;
  scales[idx] = amax / 16129.f;                 // amax / 127^2
  int hf = row >> 6, rr = row & 63, rg = rr >> 4, r = rr & 15;
  for (int kc = 0; kc < 4; ++kc){
    for (int q = 0; q < 4; ++q){
      unsigned b0 = 0, b1 = 0;
      for (int e = 0; e < 8; ++e){
        int k = kc * 32 + q * 8 + e;
        int v = (int)rintf(src[k] * inv);
        v = v > 127 ? 127 : (v < -127 ? -127 : v);
        unsigned bv = (unsigned)(v & 0xFF);
        if (e < 4) b0 |= bv << (8 * e);
        else       b1 |= bv << (8 * (e - 4));
      }
      dst[((size_t)(gs * 2 + hf) * 16 + rg * 4 + kc) * 64 + q * 16 + r] = make_uint2(b0, b1);
    }
  }
}

// 384 threads = 6 waves. wave w: gate g = w>>1, half hf = w&1 (rows hf*64..+63).
// ONE barrier per step. Every wave redundantly computes the full pointwise
// (rows 2L,2L+1 per lane; h_prev in registers, bit-identical across waves) and
// rebuilds its own next-step B-fragments in-register via ds_bpermute — no
// s_h / s_hb8 LDS arrays, no second barrier, no LDS latency at step top.
// s_acc / s_x double-buffered by step parity (race-free with one barrier).
__global__ __launch_bounds__(384, 2) void gru_run(const float* __restrict__ stim,
    const int*   __restrict__ swid,  const float* __restrict__ mask,
    const float* __restrict__ Win,   const float* __restrict__ binp,
    const float* __restrict__ b_hr,  const float* __restrict__ b_hz, const float* __restrict__ b_hn,
    const float* __restrict__ Wo,    const float* __restrict__ bo,
    const uint2* __restrict__ Wpk,   const float* __restrict__ Wsc,
    float* __restrict__ out)
{
  const int b   = blockIdx.x;
  const int tid = threadIdx.x;
  const int w   = tid >> 6;
  const int L   = tid & 63;
  const int g   = w >> 1;
  const int hf  = w & 1;

  __shared__ uint4          s_stim2[T_];        // 8 KB  bf16 stim pairs
  __shared__ float          s_mask[T_];         // 2 KB
  __shared__ unsigned short s_sid[T_];          // 1 KB
  __shared__ float          s_b[3*NSW*H_];      // 9 KB  fp32 biases [g][s][i]
  __shared__ float          s_scale[3*NSW*H_];  // 9 KB  dequant factors [gs][row]
  __shared__ float          s_x[2*3*H_];        // 3 KB  input projections (dbuf)
  __shared__ float          s_acc[2*3*H_];      // 3 KB  matvec results (dbuf)

  // ---- init LDS ----
  for (int k = tid; k < T_; k += 384){
    const float* sp = stim + (size_t)b * T_ * 8 + (size_t)k * 8;
    uint4 o;
    o.x = pack2(sp[0], sp[1]); o.y = pack2(sp[2], sp[3]);
    o.z = pack2(sp[4], sp[5]); o.w = pack2(sp[6], sp[7]);
    s_stim2[k] = o;
    s_mask[k] = mask[(size_t)b * T_ + k];
    int ss = swid[(size_t)b * T_ + k];
    s_sid[k] = (unsigned short)(ss < 0 ? 0 : (ss > NSW - 1 ? NSW - 1 : ss));
  }
  for (int k = tid; k < 3 * NSW * H_; k += 384){
    int gg = k / (NSW * H_); int rr = k % (NSW * H_);
    const float* bp = (gg == 0) ? b_hr : (gg == 1) ? b_hz : b_hn;
    s_b[k] = bp[rr];
    s_scale[k] = Wsc[k];
  }

  // input-projection row for output row tid
  unsigned winp[4];
  #pragma unroll
  for (int e = 0; e < 4; ++e)
    winp[e] = pack2(Win[(size_t)tid * 8 + 2*e], Win[(size_t)tid * 8 + 2*e + 1]);
  const float binr = binp[tid];

  // output projection weights: lane L owns rows 2L, 2L+1 (waves 2,3 store)
  float wo0 = 0.f, wo1 = 0.f, bo_r = 0.f;
  const int kk = (w == 3) ? 1 : 0;
  if (g == 1){
    wo0 = Wo[kk * H_ + 2 * L];
    wo1 = Wo[kk * H_ + 2 * L + 1];
    bo_r = bo[kk];
  }

  const bool colv = (L & 15) == 0;
  const int  quad = L >> 4;
  float* outp = out + (size_t)b * T_ * 2;

  // ---- preload ALL 6 switch-sets' A fragments (same path as round-0) ----
  uint2 Af[6][16];
  #pragma unroll
  for (int s = 0; s < 6; ++s){
    const volatile unsigned* vp =
      (const volatile unsigned*)(Wpk + ((size_t)((g * NSW + s) * 2 + hf) * 16) * 64 + L);
    #pragma unroll
    for (int j = 0; j < 16; ++j){
      Af[s][j].x = vp[2 * (j * 64)];
      Af[s][j].y = vp[2 * (j * 64) + 1];
    }
  }

  __syncthreads();

  int sc = __builtin_amdgcn_readfirstlane((int)s_sid[0]);
  long bl0 = 0, bl1 = 0, bl2 = 0, bl3 = 0;    // h == 0 at t=0
  float h0p = 0.f, h1p = 0.f;                 // h_prev rows 2L, 2L+1
  const int r0 = 2 * L;

#define MM(S)                                                                  \
    _Pragma("unroll")                                                          \
    for (int rg = 0; rg < 4; ++rg){                                            \
      i32x4 a = {0, 0, 0, 0};                                                  \
      a = __builtin_amdgcn_mfma_i32_16x16x32_i8(                               \
            __builtin_bit_cast(long, Af[S][rg*4+0]), bl0, a, 0, 0, 0);         \
      a = __builtin_amdgcn_mfma_i32_16x16x32_i8(                               \
            __builtin_bit_cast(long, Af[S][rg*4+1]), bl1, a, 0, 0, 0);         \
      a = __builtin_amdgcn_mfma_i32_16x16x32_i8(                               \
            __builtin_bit_cast(long, Af[S][rg*4+2]), bl2, a, 0, 0, 0);         \
      a = __builtin_amdgcn_mfma_i32_16x16x32_i8(                               \
            __builtin_bit_cast(long, Af[S][rg*4+3]), bl3, a, 0, 0, 0);         \
      accv[rg] = a;                                                            \
    }

  #pragma unroll 1
  for (int t = 0; t < T_; ++t){
    float* sxb = s_x  + (t & 1) * (3 * H_);
    float* sab = s_acc + (t & 1) * (3 * H_);

    // input projection x for output row tid (independent of h)
    uint4 sp = s_stim2[t];
    float x = binr;
    x = dot2bf(winp[0], sp.x, x);
    x = dot2bf(winp[1], sp.y, x);
    x = dot2bf(winp[2], sp.z, x);
    x = dot2bf(winp[3], sp.w, x);
    sxb[tid] = x;

    // matvec: B-fragments already in registers (from prev step's bpermutes)
    i32x4 accv[4];
    switch (sc){
      case 0: MM(0); break;
      case 1: MM(1); break;
      case 2: MM(2); break;
      case 3: MM(3); break;
      case 4: MM(4); break;
      default: MM(5); break;
    }

    // dequant + scatter: col-0 lanes own rows rg*16 + quad*4 + 0..3
    if (colv){
      #pragma unroll
      for (int rg = 0; rg < 4; ++rg){
        int rbase = hf * 64 + rg * 16 + quad * 4;
        f32x4 scf = *reinterpret_cast<const f32x4*>(&s_scale[(g * NSW + sc) * H_ + rbase]);
        f32x4 v;
        v.x = (float)accv[rg].x * scf.x;
        v.y = (float)accv[rg].y * scf.y;
        v.z = (float)accv[rg].z * scf.z;
        v.w = (float)accv[rg].w * scf.w;
        *reinterpret_cast<f32x4*>(&sab[g * H_ + rbase]) = v;
      }
    }

    lds_barrier();   // the ONLY barrier: s_acc + s_x visible

    // ---- phase 2: every wave, all 64 lanes, rows 2L and 2L+1 ----
    const float2 a_r = *reinterpret_cast<const float2*>(&sab[r0]);
    const float2 a_z = *reinterpret_cast<const float2*>(&sab[H_ + r0]);
    const float2 a_n = *reinterpret_cast<const float2*>(&sab[2*H_ + r0]);
    const float2 x_r = *reinterpret_cast<const float2*>(&sxb[r0]);
    const float2 x_z = *reinterpret_cast<const float2*>(&sxb[H_ + r0]);
    const float2 x_n = *reinterpret_cast<const float2*>(&sxb[2*H_ + r0]);
    const float2 b_r = *reinterpret_cast<const float2*>(&s_b[(0*NSW + sc) * H_ + r0]);
    const float2 b_z = *reinterpret_cast<const float2*>(&s_b[(1*NSW + sc) * H_ + r0]);
    const float2 b_n = *reinterpret_cast<const float2*>(&s_b[(2*NSW + sc) * H_ + r0]);
    const float mt = s_mask[t];
    int tn = (t + 1 < T_) ? (t + 1) : (T_ - 1);
    int sidn = (int)s_sid[tn];                  // issued early, used at loop end

    float ho0, ho1;
    {
      float hr = a_r.x + b_r.x, hz = a_z.x + b_z.x, hn = a_n.x + b_n.x;
      float r = 1.f / (1.f + __expf(-(x_r.x + hr)));
      float z = 1.f / (1.f + __expf(-(x_z.x + hz)));
      float e = __expf(2.f * (x_n.x + r * hn));
      float n = 1.f - 2.f / (e + 1.f);
      float hnew = (1.f - z) * n + z * h0p;
      ho0 = mt * hnew + (1.f - mt) * h0p;
    }
    {
      float hr = a_r.y + b_r.y, hz = a_z.y + b_z.y, hn = a_n.y + b_n.y;
      float r = 1.f / (1.f + __expf(-(x_r.y + hr)));
      float z = 1.f / (1.f + __expf(-(x_z.y + hz)));
      float e = __expf(2.f * (x_n.y + r * hn));
      float n = 1.f - 2.f / (e + 1.f);
      float hnew = (1.f - z) * n + z * h1p;
      ho1 = mt * hnew + (1.f - mt) * h1p;
    }
    h0p = ho0; h1p = ho1;

    // quantize + in-wave redistribution into next-step B-fragments
    int q0 = (int)rintf(ho0 * 127.f);
    q0 = q0 > 127 ? 127 : (q0 < -127 ? -127 : q0);
    int q1 = (int)rintf(ho1 * 127.f);
    q1 = q1 > 127 ? 127 : (q1 < -127 ? -127 : q1);
    int u16 = (q0 & 0xFF) | ((q1 & 0xFF) << 8);
    // pack: even lane 2m gets rows 4m..4m+3 in one u32
    int oth = __builtin_amdgcn_ds_bpermute(4 * (L ^ 1), u16);
    int u32p = (u16 & 0xFFFF) | (oth << 16);
    // gather: chunk kc for col-0 lane (quad q) = rows kc*32+q*8..+7
    //   -> u32s at lanes 16*kc+4*q and 16*kc+4*q+2
    {
      int lo, hi;
      lo = __builtin_amdgcn_ds_bpermute(4 * ( 0 + 4*quad),     u32p);
      hi = __builtin_amdgcn_ds_bpermute(4 * ( 0 + 4*quad + 2), u32p);
      bl0 = (long)(((unsigned long)(unsigned)lo) | (((unsigned long)(unsigned)hi) << 32));
      lo = __builtin_amdgcn_ds_bpermute(4 * (16 + 4*quad),     u32p);
      hi = __builtin_amdgcn_ds_bpermute(4 * (16 + 4*quad + 2), u32p);
      bl1 = (long)(((unsigned long)(unsigned)lo) | (((unsigned long)(unsigned)hi) << 32));
      lo = __builtin_amdgcn_ds_bpermute(4 * (32 + 4*quad),     u32p);
      hi = __builtin_amdgcn_ds_bpermute(4 * (32 + 4*quad + 2), u32p);
      bl2 = (long)(((unsigned long)(unsigned)lo) | (((unsigned long)(unsigned)hi) << 32));
      lo = __builtin_amdgcn_ds_bpermute(4 * (48 + 4*quad),     u32p);
      hi = __builtin_amdgcn_ds_bpermute(4 * (48 + 4*quad + 2), u32p);
      bl3 = (long)(((unsigned long)(unsigned)lo) | (((unsigned long)(unsigned)hi) << 32));
    }

    // output projection: waves 2,3 reduce in-register ho over the wave
    if (g == 1){
      float p = wo0 * ho0 + wo1 * ho1;
      p += __shfl_xor(p, 32); p += __shfl_xor(p, 16); p += __shfl_xor(p, 8);
      p += __shfl_xor(p, 4);  p += __shfl_xor(p, 2);  p += __shfl_xor(p, 1);
      if (L == 0) outp[t * 2 + kk] = p + bo_r;
    }

    sc = __builtin_amdgcn_readfirstlane(sidn);
  }
#undef MM
}

extern "C" void kernel_launch(void* const* d_in, const int* in_sizes, int n_in,
                              void* d_out, int out_size, void* d_ws, size_t ws_size,
                              hipStream_t stream) {
  const float* stim = (const float*)d_in[0];
  const int*   swid = (const int*)  d_in[1];
  const float* mask = (const float*)d_in[2];
  const float* Win  = (const float*)d_in[3];
  const float* binp = (const float*)d_in[4];
  const float* Whr  = (const float*)d_in[5];
  const float* Whz  = (const float*)d_in[6];
  const float* Whn  = (const float*)d_in[7];
  const float* bhr  = (const float*)d_in[8];
  const float* bhz  = (const float*)d_in[9];
  const float* bhn  = (const float*)d_in[10];
  const float* Wo   = (const float*)d_in[11];
  const float* bo   = (const float*)d_in[12];

  uint2* wpk = (uint2*)d_ws;                       // 294912 B packed int8 frags
  float* wsc = (float*)((char*)d_ws + 294912);     // 9216 B row scales

  pack_weights_i8<<<9, 256, 0, stream>>>(Whr, Whz, Whn, wpk, wsc);
  gru_run<<<B_, 384, 0, stream>>>(stim, swid, mask, Win, binp,
                                  bhr, bhz, bhn, Wo, bo, wpk, wsc, (float*)d_out);
}

// Round 3
// 602.352 us; speedup vs baseline: 1.2396x; 1.2396x over previous
//
#include <hip/hip_runtime.h>
#include <stdint.h>

#define B_  256
#define T_  512
#define H_  128
#define NSW 6

typedef __bf16 bf2_t  __attribute__((ext_vector_type(2)));
typedef int    i32x4  __attribute__((ext_vector_type(4)));
typedef float  f32x4  __attribute__((ext_vector_type(4)));

// float -> bf16 round-to-nearest-even
__device__ __forceinline__ unsigned short f2bf(float f){
  unsigned u = __float_as_uint(f);
  unsigned r = u + 0x7FFFu + ((u >> 16) & 1u);
  return (unsigned short)(r >> 16);
}
__device__ __forceinline__ unsigned pack2(float a, float b){
  return (unsigned)f2bf(a) | ((unsigned)f2bf(b) << 16);
}
__device__ __forceinline__ float dot2bf(unsigned wpair, unsigned hpair, float acc){
  return __builtin_amdgcn_fdot2_f32_bf16(__builtin_bit_cast(bf2_t, wpair),
                                         __builtin_bit_cast(bf2_t, hpair), acc, false);
}
__device__ __forceinline__ void lds_barrier(){
  asm volatile("s_waitcnt lgkmcnt(0)\ns_barrier" ::: "memory");
}

// Per-row symmetric int8 quantization into MFMA A-fragment order, tiled over
// the CONCATENATED 384-row [Wr; Wz; Wn] matrix (24 tiles of 16 rows).
// uint2 idx = (s*96 + tau*4 + kc)*64 + q*16 + r holds int8 of
//   Wcat[s][row = 16*tau + r][k = kc*32 + q*8 + 0..7]  (byte e = k offset e)
// scales[s*384 + row] = rowmax / (127*127)  (dequant factor incl. h scale 1/127)
__global__ __launch_bounds__(256) void pack_weights_i8(const float* __restrict__ Wr,
                                                       const float* __restrict__ Wz,
                                                       const float* __restrict__ Wn,
                                                       uint2* __restrict__ dst,
                                                       float* __restrict__ scales){
  int idx = blockIdx.x * 256 + threadIdx.x;     // (s, row384)
  if (idx >= NSW * 384) return;
  int s   = idx / 384;
  int row = idx % 384;
  int g   = row >> 7;                            // gate 0..2
  int rr  = row & 127;                           // row within gate
  const float* W = (g == 0) ? Wr : (g == 1) ? Wz : Wn;
  const float* src = W + (size_t)s * (H_*H_) + (size_t)rr * H_;
  float amax = 0.f;
  for (int j = 0; j < H_; ++j) amax = fmaxf(amax, fabsf(src[j]));
  amax = fmaxf(amax, 1e-20f);
  float inv = 127.f / amax;
  scales[idx] = amax / 16129.f;                 // amax / 127^2
  int tau = row >> 4, r = row & 15;
  for (int kc = 0; kc < 4; ++kc){
    for (int q = 0; q < 4; ++q){
      unsigned b0 = 0, b1 = 0;
      for (int e = 0; e < 8; ++e){
        int k = kc * 32 + q * 8 + e;
        int v = (int)rintf(src[k] * inv);
        v = v > 127 ? 127 : (v < -127 ? -127 : v);
        unsigned bv = (unsigned)(v & 0xFF);
        if (e < 4) b0 |= bv << (8 * e);
        else       b1 |= bv << (8 * (e - 4));
      }
      dst[((size_t)(s * 96 + tau * 4 + kc)) * 64 + q * 16 + r] = make_uint2(b0, b1);
    }
  }
}

// 512 threads = 8 waves (balanced 2/SIMD). Wave w owns tiles 3w..3w+2 of the
// 384-row concatenated [r;z;n] weight matrix: per-wave payload = 6 sets x 12
// uint2 = 144 VGPR, which together with ~110 arch regs FITS the 256-reg/wave
// cap -> full register residency, no scratch reloads in the switch.
// Same two-barrier skeleton as the 555us baseline, plus: sid read hoisted one
// step early, bias folded into dequant, B-frag addresses hoisted.
__global__ __launch_bounds__(512, 2) void gru_run(const float* __restrict__ stim,
    const int*   __restrict__ swid,  const float* __restrict__ mask,
    const float* __restrict__ Win,   const float* __restrict__ binp,
    const float* __restrict__ b_hr,  const float* __restrict__ b_hz, const float* __restrict__ b_hn,
    const float* __restrict__ Wo,    const float* __restrict__ bo,
    const uint2* __restrict__ Wpk,   const float* __restrict__ Wsc,
    float* __restrict__ out)
{
  const int b   = blockIdx.x;
  const int tid = threadIdx.x;
  const int w   = tid >> 6;          // 0..7
  const int L   = tid & 63;

  __shared__ uint4          s_stim2[T_];        // 8 KB  bf16 stim pairs
  __shared__ float          s_mask[T_];         // 2 KB
  __shared__ unsigned short s_sid[T_];          // 1 KB
  __shared__ __align__(16) float s_b[NSW*384];     // 9 KB  biases [s][row384]
  __shared__ __align__(16) float s_scale[NSW*384]; // 9 KB  dequant factors [s][row384]
  __shared__ __align__(16) float s_x[384];         // 1.5 KB input projections
  __shared__ __align__(16) float s_acc[384];       // 1.5 KB matvec + bias (dequantized)
  __shared__ float          s_h[H_];            // fp32 h
  __shared__ __align__(16) char s_hb8[160];     // h int8 [0,128) + zero pad [128,160)

  // ---- init LDS ----
  for (int k = tid; k < T_; k += 512){
    const float* sp = stim + (size_t)b * T_ * 8 + (size_t)k * 8;
    uint4 o;
    o.x = pack2(sp[0], sp[1]); o.y = pack2(sp[2], sp[3]);
    o.z = pack2(sp[4], sp[5]); o.w = pack2(sp[6], sp[7]);
    s_stim2[k] = o;
    s_mask[k] = mask[(size_t)b * T_ + k];
    int ss = swid[(size_t)b * T_ + k];
    s_sid[k] = (unsigned short)(ss < 0 ? 0 : (ss > NSW - 1 ? NSW - 1 : ss));
  }
  for (int k = tid; k < NSW * 384; k += 512){
    int s = k / 384; int row = k % 384;
    int g = row >> 7; int rr = row & 127;
    const float* bp = (g == 0) ? b_hr : (g == 1) ? b_hz : b_hn;
    s_b[k] = bp[s * H_ + rr];
    s_scale[k] = Wsc[k];
  }
  if (tid < H_) s_h[tid] = 0.f;
  if (tid < 40) ((int*)s_hb8)[tid] = 0;

  // input-projection row for output row tid (only 384 rows exist)
  unsigned winp[4] = {0, 0, 0, 0};
  float binr = 0.f;
  if (tid < 384){
    #pragma unroll
    for (int e = 0; e < 4; ++e)
      winp[e] = pack2(Win[(size_t)tid * 8 + 2*e], Win[(size_t)tid * 8 + 2*e + 1]);
    binr = binp[tid];
  }

  // output projection: waves 2 (logit 0) and 3 (logit 1)
  float wo_a = 0.f, wo_b = 0.f, bo_r = 0.f;
  const int kk = w & 1;
  const bool ow = (w == 2) || (w == 3);
  if (ow){
    wo_a = Wo[kk * H_ + L];
    wo_b = Wo[kk * H_ + 64 + L];
    bo_r = bo[kk];
  }

  const bool colv = (L & 15) == 0;
  const int  quad = L >> 4;
  float* outp = out + (size_t)b * T_ * 2;

  // B-frag LDS byte addresses (compile-time per lane; zero pad for non-col)
  const int ob0 = colv ? (0 * 32 + quad * 8) : 128;
  const int ob1 = colv ? (1 * 32 + quad * 8) : 128;
  const int ob2 = colv ? (2 * 32 + quad * 8) : 128;
  const int ob3 = colv ? (3 * 32 + quad * 8) : 128;

  // ---- preload ALL 6 switch-sets' A fragments into registers (volatile:
  //      cannot be sunk into the loop or rematerialized). 6 x 12 x 8B = 144 regs.
  uint2 Af[6][12];
  #pragma unroll
  for (int s = 0; s < 6; ++s){
    const volatile unsigned* vp =
      (const volatile unsigned*)(Wpk + ((size_t)(s * 96 + 12 * w)) * 64 + L);
    #pragma unroll
    for (int j = 0; j < 12; ++j){
      Af[s][j].x = vp[2 * (j * 64)];
      Af[s][j].y = vp[2 * (j * 64) + 1];
    }
  }

  __syncthreads();

  int sc = __builtin_amdgcn_readfirstlane((int)s_sid[0]);

#define MM(S)                                                                  \
    _Pragma("unroll")                                                          \
    for (int tl = 0; tl < 3; ++tl){                                            \
      i32x4 a = {0, 0, 0, 0};                                                  \
      a = __builtin_amdgcn_mfma_i32_16x16x32_i8(                               \
            __builtin_bit_cast(long, Af[S][tl*4+0]), bl0, a, 0, 0, 0);         \
      a = __builtin_amdgcn_mfma_i32_16x16x32_i8(                               \
            __builtin_bit_cast(long, Af[S][tl*4+1]), bl1, a, 0, 0, 0);         \
      a = __builtin_amdgcn_mfma_i32_16x16x32_i8(                               \
            __builtin_bit_cast(long, Af[S][tl*4+2]), bl2, a, 0, 0, 0);         \
      a = __builtin_amdgcn_mfma_i32_16x16x32_i8(                               \
            __builtin_bit_cast(long, Af[S][tl*4+3]), bl3, a, 0, 0, 0);         \
      accv[tl] = a;                                                            \
    }

  #pragma unroll 1
  for (int t = 0; t < T_; ++t){
    // next-step sid: vector LDS read issued at step top, readfirstlane at end
    int tn = (t + 1 < T_) ? (t + 1) : (T_ - 1);
    int sidn = (int)s_sid[tn];

    // B fragments: col-0 lanes read h int8 (8 B at k = kc*32+quad*8); others zero pad
    long bl0 = *(const long*)(s_hb8 + ob0);
    long bl1 = *(const long*)(s_hb8 + ob1);
    long bl2 = *(const long*)(s_hb8 + ob2);
    long bl3 = *(const long*)(s_hb8 + ob3);

    // input projection x for output row tid (independent of h)
    if (tid < 384){
      uint4 sp = s_stim2[t];
      float x = binr;
      x = dot2bf(winp[0], sp.x, x);
      x = dot2bf(winp[1], sp.y, x);
      x = dot2bf(winp[2], sp.z, x);
      x = dot2bf(winp[3], sp.w, x);
      s_x[tid] = x;
    }

    // matvec from register-resident weights (wave-uniform sid dispatch)
    i32x4 accv[3];
    switch (sc){
      case 0: MM(0); break;
      case 1: MM(1); break;
      case 2: MM(2); break;
      case 3: MM(3); break;
      case 4: MM(4); break;
      default: MM(5); break;
    }

    // dequant + bias + scatter: col-0 lanes own rows (3w+tl)*16 + quad*4 + 0..3
    if (colv){
      #pragma unroll
      for (int tl = 0; tl < 3; ++tl){
        int rbase = (3 * w + tl) * 16 + quad * 4;
        f32x4 scf = *reinterpret_cast<const f32x4*>(&s_scale[sc * 384 + rbase]);
        f32x4 bsf = *reinterpret_cast<const f32x4*>(&s_b[sc * 384 + rbase]);
        f32x4 v;
        v.x = (float)accv[tl].x * scf.x + bsf.x;
        v.y = (float)accv[tl].y * scf.y + bsf.y;
        v.z = (float)accv[tl].z * scf.z + bsf.z;
        v.w = (float)accv[tl].w * scf.w + bsf.w;
        *reinterpret_cast<f32x4*>(&s_acc[rbase]) = v;
      }
    }

    lds_barrier();   // B1: s_acc + s_x visible

    if (tid < H_){
      const int i = tid;
      float ar = s_acc[i];            // matvec + bias
      float az = s_acc[H_ + i];
      float an = s_acc[2*H_ + i];
      float xr = s_x[i], xz = s_x[H_ + i], xn = s_x[2*H_ + i];
      float r = 1.f / (1.f + __expf(-(xr + ar)));
      float z = 1.f / (1.f + __expf(-(xz + az)));
      float e = __expf(2.f * (xn + r * an));       // tanh(a) = 1 - 2/(e^{2a}+1)
      float n = 1.f - 2.f / (e + 1.f);
      float hprev = s_h[i];
      float hnew  = (1.f - z) * n + z * hprev;
      float mt    = s_mask[t];
      float ho    = mt * hnew + (1.f - mt) * hprev;
      s_h[i] = ho;
      int qi = (int)rintf(ho * 127.f);
      qi = qi > 127 ? 127 : (qi < -127 ? -127 : qi);
      s_hb8[i] = (char)qi;
    }

    lds_barrier();   // B2: h visible

    if (ow){
      float p = wo_a * s_h[L] + wo_b * s_h[64 + L];
      p += __shfl_down(p, 32); p += __shfl_down(p, 16); p += __shfl_down(p, 8);
      p += __shfl_down(p, 4);  p += __shfl_down(p, 2);  p += __shfl_down(p, 1);
      if (L == 0) outp[t * 2 + kk] = p + bo_r;
    }

    sc = __builtin_amdgcn_readfirstlane(sidn);
  }
#undef MM
}

extern "C" void kernel_launch(void* const* d_in, const int* in_sizes, int n_in,
                              void* d_out, int out_size, void* d_ws, size_t ws_size,
                              hipStream_t stream) {
  const float* stim = (const float*)d_in[0];
  const int*   swid = (const int*)  d_in[1];
  const float* mask = (const float*)d_in[2];
  const float* Win  = (const float*)d_in[3];
  const float* binp = (const float*)d_in[4];
  const float* Whr  = (const float*)d_in[5];
  const float* Whz  = (const float*)d_in[6];
  const float* Whn  = (const float*)d_in[7];
  const float* bhr  = (const float*)d_in[8];
  const float* bhz  = (const float*)d_in[9];
  const float* bhn  = (const float*)d_in[10];
  const float* Wo   = (const float*)d_in[11];
  const float* bo   = (const float*)d_in[12];

  uint2* wpk = (uint2*)d_ws;                       // 294912 B packed int8 frags
  float* wsc = (float*)((char*)d_ws + 294912);     // 9216 B row scales

  pack_weights_i8<<<9, 256, 0, stream>>>(Whr, Whz, Whn, wpk, wsc);
  gru_run<<<B_, 512, 0, stream>>>(stim, swid, mask, Win, binp,
                                  bhr, bhz, bhn, Wo, bo, wpk, wsc, (float*)d_out);
}

// Round 4
// 511.188 us; speedup vs baseline: 1.4606x; 1.1783x over previous
//
#include <hip/hip_runtime.h>
#include <stdint.h>

#define B_  256
#define T_  512
#define H_  128
#define NSW 6

typedef __bf16 bf2_t  __attribute__((ext_vector_type(2)));
typedef int    i32x4  __attribute__((ext_vector_type(4)));
typedef float  f32x4  __attribute__((ext_vector_type(4)));

// float -> bf16 round-to-nearest-even
__device__ __forceinline__ unsigned short f2bf(float f){
  unsigned u = __float_as_uint(f);
  unsigned r = u + 0x7FFFu + ((u >> 16) & 1u);
  return (unsigned short)(r >> 16);
}
__device__ __forceinline__ unsigned pack2(float a, float b){
  return (unsigned)f2bf(a) | ((unsigned)f2bf(b) << 16);
}
__device__ __forceinline__ float dot2bf(unsigned wpair, unsigned hpair, float acc){
  return __builtin_amdgcn_fdot2_f32_bf16(__builtin_bit_cast(bf2_t, wpair),
                                         __builtin_bit_cast(bf2_t, hpair), acc, false);
}
__device__ __forceinline__ void lds_barrier(){
  asm volatile("s_waitcnt lgkmcnt(0)\ns_barrier" ::: "memory");
}

// Per-row symmetric int8 quantization into MFMA *B*-fragment order (W^T).
// Tile (s, g', w) covers output rows i = 16w..16w+15 of gate g'.
// uint2 idx = ((s*24 + g'*8 + w)*4 + kc)*64 + q*16 + c holds int8 of
//   W_g'[s][i = 16w + c][k = kc*32 + q*8 + 0..7]   (byte e = k offset e)
// i.e. B[k][n]: col n = lane&15 = c, k = (lane>>4)*8+e  (A/B layouts symmetric).
// scales[s*384 + g'*128 + i] = rowmax / (127*127)
__global__ __launch_bounds__(256) void pack_weights_i8(const float* __restrict__ Wr,
                                                       const float* __restrict__ Wz,
                                                       const float* __restrict__ Wn,
                                                       uint2* __restrict__ dst,
                                                       float* __restrict__ scales){
  int idx = blockIdx.x * 256 + threadIdx.x;     // (s, row384)
  if (idx >= NSW * 384) return;
  int s   = idx / 384;
  int row = idx % 384;
  int gp  = row >> 7;                            // gate 0..2
  int i   = row & 127;                           // output row within gate
  const float* W = (gp == 0) ? Wr : (gp == 1) ? Wz : Wn;
  const float* src = W + (size_t)s * (H_*H_) + (size_t)i * H_;
  float amax = 0.f;
  for (int j = 0; j < H_; ++j) amax = fmaxf(amax, fabsf(src[j]));
  amax = fmaxf(amax, 1e-20f);
  float inv = 127.f / amax;
  scales[idx] = amax / 16129.f;                 // amax / 127^2
  int w = i >> 4, c = i & 15;
  for (int kc = 0; kc < 4; ++kc){
    for (int q = 0; q < 4; ++q){
      unsigned b0 = 0, b1 = 0;
      for (int e = 0; e < 8; ++e){
        int k = kc * 32 + q * 8 + e;
        int v = (int)rintf(src[k] * inv);
        v = v > 127 ? 127 : (v < -127 ? -127 : v);
        unsigned bv = (unsigned)(v & 0xFF);
        if (e < 4) b0 |= bv << (8 * e);
        else       b1 |= bv << (8 * (e - 4));
      }
      dst[((size_t)((s * 24 + gp * 8 + w) * 4 + kc)) * 64 + q * 16 + c] = make_uint2(b0, b1);
    }
  }
}

// 512 threads = 8 waves. Transposed MFMA: A = h (row 0 only), B = W^T.
// Wave w owns h rows 16w..16w+15 for ALL THREE gates -> lane l<16 holds
// (ar,az,an) for h-row 16w+l in-register after MFMA. Pointwise fully
// in-register (h_prev in reg, x via 12 in-lane fdot2, scale+bias one early
// LDS read). ONE barrier per step; h exchanged via parity-double-buffered
// int8 (MFMA A-frag) + f32 (output proj) LDS slots.
__global__ __launch_bounds__(512, 2) void gru_run(const float* __restrict__ stim,
    const int*   __restrict__ swid,  const float* __restrict__ mask,
    const float* __restrict__ Win,   const float* __restrict__ binp,
    const float* __restrict__ b_hr,  const float* __restrict__ b_hz, const float* __restrict__ b_hn,
    const float* __restrict__ Wo,    const float* __restrict__ bo,
    const uint2* __restrict__ Wpk,   const float* __restrict__ Wsc,
    float* __restrict__ out)
{
  const int b   = blockIdx.x;
  const int tid = threadIdx.x;
  const int w   = tid >> 6;          // 0..7
  const int L   = tid & 63;

  __shared__ uint4          s_stim2[T_];        // 8 KB  bf16 stim pairs
  __shared__ float          s_mask[T_];         // 2 KB
  __shared__ unsigned short s_sid[T_];          // 1 KB
  __shared__ __align__(16) float2 s_sb[NSW*384];   // 18 KB {scale, bias} per (s,row384)
  __shared__ __align__(16) char   s_hb8[2][192];   // int8 h slots; [128..160) zero pad
  __shared__ __align__(16) float  s_hf[2][H_];     // f32 h slots (output projection)

  // ---- init LDS ----
  for (int k = tid; k < T_; k += 512){
    const float* sp = stim + (size_t)b * T_ * 8 + (size_t)k * 8;
    uint4 o;
    o.x = pack2(sp[0], sp[1]); o.y = pack2(sp[2], sp[3]);
    o.z = pack2(sp[4], sp[5]); o.w = pack2(sp[6], sp[7]);
    s_stim2[k] = o;
    s_mask[k] = mask[(size_t)b * T_ + k];
    int ss = swid[(size_t)b * T_ + k];
    s_sid[k] = (unsigned short)(ss < 0 ? 0 : (ss > NSW - 1 ? NSW - 1 : ss));
  }
  for (int k = tid; k < NSW * 384; k += 512){
    int s = k / 384; int row = k % 384;
    int gp = row >> 7; int i = row & 127;
    const float* bp = (gp == 0) ? b_hr : (gp == 1) ? b_hz : b_hn;
    s_sb[k] = make_float2(Wsc[k], bp[s * H_ + i]);
  }
  if (tid < 96) ((int*)s_hb8)[tid] = 0;         // zero both int8 slots incl. pad

  // in-lane x-projection weights: lane l<16 of wave w owns rows gp*128+16w+l
  unsigned winp[3][4] = {{0,0,0,0},{0,0,0,0},{0,0,0,0}};
  float binr[3] = {0.f, 0.f, 0.f};
  if (L < 16){
    #pragma unroll
    for (int gp = 0; gp < 3; ++gp){
      int row = gp * 128 + 16 * w + L;
      #pragma unroll
      for (int e = 0; e < 4; ++e)
        winp[gp][e] = pack2(Win[(size_t)row * 8 + 2*e], Win[(size_t)row * 8 + 2*e + 1]);
      binr[gp] = binp[row];
    }
  }

  // output projection: waves 2 (logit 0) and 3 (logit 1)
  float wo_a = 0.f, wo_b = 0.f, bo_r = 0.f;
  const int kk = w & 1;
  const bool ow = (w == 2) || (w == 3);
  if (ow){
    wo_a = Wo[kk * H_ + L];
    wo_b = Wo[kk * H_ + 64 + L];
    bo_r = bo[kk];
  }

  const bool colv = (L & 15) == 0;
  const int  quad = L >> 4;
  float* outp = out + (size_t)b * T_ * 2;

  // A-frag (h) LDS byte offsets within a slot (zero pad for non-col lanes)
  const int ob0 = colv ? (0 * 32 + quad * 8) : 128;
  const int ob1 = colv ? (1 * 32 + quad * 8) : 128;
  const int ob2 = colv ? (2 * 32 + quad * 8) : 128;
  const int ob3 = colv ? (3 * 32 + quad * 8) : 128;

  // ---- preload ALL 6 switch-sets' B fragments (W^T) into registers/AGPRs.
  //      volatile: cannot be sunk into the loop or rematerialized. 144 regs.
  uint2 Bf[6][12];
  #pragma unroll
  for (int s = 0; s < 6; ++s){
    #pragma unroll
    for (int gp = 0; gp < 3; ++gp){
      const volatile unsigned* vp =
        (const volatile unsigned*)(Wpk + ((size_t)((s * 24 + gp * 8 + w) * 4)) * 64 + L);
      #pragma unroll
      for (int kc = 0; kc < 4; ++kc){
        Bf[s][gp*4+kc].x = vp[2 * (kc * 64)];
        Bf[s][gp*4+kc].y = vp[2 * (kc * 64) + 1];
      }
    }
  }

  __syncthreads();

  int sc = __builtin_amdgcn_readfirstlane((int)s_sid[0]);
  float hprev = 0.f;                 // lane l<16 of wave w: h row 16w+l

#define MFMA1(BL, FR, A) __builtin_amdgcn_mfma_i32_16x16x32_i8( \
        (BL), __builtin_bit_cast(long, (FR)), (A), 0, 0, 0)
#define MM(S)                                                                  \
    { i32x4 a;                                                                 \
      a = (i32x4){0,0,0,0};                                                    \
      a = MFMA1(bl0, Bf[S][0], a);  a = MFMA1(bl1, Bf[S][1], a);               \
      a = MFMA1(bl2, Bf[S][2], a);  a = MFMA1(bl3, Bf[S][3], a);  ac0 = a;     \
      a = (i32x4){0,0,0,0};                                                    \
      a = MFMA1(bl0, Bf[S][4], a);  a = MFMA1(bl1, Bf[S][5], a);               \
      a = MFMA1(bl2, Bf[S][6], a);  a = MFMA1(bl3, Bf[S][7], a);  ac1 = a;     \
      a = (i32x4){0,0,0,0};                                                    \
      a = MFMA1(bl0, Bf[S][8], a);  a = MFMA1(bl1, Bf[S][9], a);               \
      a = MFMA1(bl2, Bf[S][10], a); a = MFMA1(bl3, Bf[S][11], a); ac2 = a; }

  #pragma unroll 1
  for (int t = 0; t < T_; ++t){
    // next-step sid: LDS read issued early, readfirstlane at loop end
    int tn = (t + 1 < T_) ? (t + 1) : (T_ - 1);
    int sidn = (int)s_sid[tn];

    // A fragments: h_{t-1} int8 from slot (t-1)&1 == (t+1)&1
    const char* hsrc = s_hb8[(t + 1) & 1];
    long bl0 = *(const long*)(hsrc + ob0);
    long bl1 = *(const long*)(hsrc + ob1);
    long bl2 = *(const long*)(hsrc + ob2);
    long bl3 = *(const long*)(hsrc + ob3);

    // early per-lane reads (overlap MFMA): scale+bias pairs, stim, mask
    float2 sb_r = make_float2(0.f, 0.f), sb_z = sb_r, sb_n = sb_r;
    float xr = 0.f, xz = 0.f, xn = 0.f;
    const float mt = s_mask[t];
    if (L < 16){
      int base = sc * 384 + 16 * w + L;
      sb_r = s_sb[base];
      sb_z = s_sb[base + 128];
      sb_n = s_sb[base + 256];
      uint4 sp = s_stim2[t];
      xr = binr[0];
      xr = dot2bf(winp[0][0], sp.x, xr); xr = dot2bf(winp[0][1], sp.y, xr);
      xr = dot2bf(winp[0][2], sp.z, xr); xr = dot2bf(winp[0][3], sp.w, xr);
      xz = binr[1];
      xz = dot2bf(winp[1][0], sp.x, xz); xz = dot2bf(winp[1][1], sp.y, xz);
      xz = dot2bf(winp[1][2], sp.z, xz); xz = dot2bf(winp[1][3], sp.w, xz);
      xn = binr[2];
      xn = dot2bf(winp[2][0], sp.x, xn); xn = dot2bf(winp[2][1], sp.y, xn);
      xn = dot2bf(winp[2][2], sp.z, xn); xn = dot2bf(winp[2][3], sp.w, xn);
    }

    // matvec: C[0][n] lands in lanes 0..15, reg .x  (A rows 1..15 are zero)
    i32x4 ac0, ac1, ac2;
    switch (sc){
      case 0: MM(0); break;
      case 1: MM(1); break;
      case 2: MM(2); break;
      case 3: MM(3); break;
      case 4: MM(4); break;
      default: MM(5); break;
    }

    // dequant + pointwise, fully in-register (lane l<16: h row 16w+l)
    if (L < 16){
      float ar = (float)ac0.x * sb_r.x + sb_r.y;
      float az = (float)ac1.x * sb_z.x + sb_z.y;
      float an = (float)ac2.x * sb_n.x + sb_n.y;
      float r = 1.f / (1.f + __expf(-(xr + ar)));
      float z = 1.f / (1.f + __expf(-(xz + az)));
      float e = __expf(2.f * (xn + r * an));       // tanh(a) = 1 - 2/(e^{2a}+1)
      float n = 1.f - 2.f / (e + 1.f);
      float hnew = (1.f - z) * n + z * hprev;
      float ho   = mt * hnew + (1.f - mt) * hprev;
      hprev = ho;
      s_hf[t & 1][16 * w + L] = ho;
      int qi = (int)rintf(ho * 127.f);
      qi = qi > 127 ? 127 : (qi < -127 ? -127 : qi);
      s_hb8[t & 1][16 * w + L] = (char)qi;
    }

    lds_barrier();   // the ONLY barrier: h_t (int8 + f32) visible

    // output projection (off the h critical path; overlaps next step top)
    if (ow){
      const float* hf = s_hf[t & 1];
      float p = wo_a * hf[L] + wo_b * hf[64 + L];
      p += __shfl_down(p, 32); p += __shfl_down(p, 16); p += __shfl_down(p, 8);
      p += __shfl_down(p, 4);  p += __shfl_down(p, 2);  p += __shfl_down(p, 1);
      if (L == 0) outp[t * 2 + kk] = p + bo_r;
    }

    sc = __builtin_amdgcn_readfirstlane(sidn);
  }
#undef MM
#undef MFMA1
}

extern "C" void kernel_launch(void* const* d_in, const int* in_sizes, int n_in,
                              void* d_out, int out_size, void* d_ws, size_t ws_size,
                              hipStream_t stream) {
  const float* stim = (const float*)d_in[0];
  const int*   swid = (const int*)  d_in[1];
  const float* mask = (const float*)d_in[2];
  const float* Win  = (const float*)d_in[3];
  const float* binp = (const float*)d_in[4];
  const float* Whr  = (const float*)d_in[5];
  const float* Whz  = (const float*)d_in[6];
  const float* Whn  = (const float*)d_in[7];
  const float* bhr  = (const float*)d_in[8];
  const float* bhz  = (const float*)d_in[9];
  const float* bhn  = (const float*)d_in[10];
  const float* Wo   = (const float*)d_in[11];
  const float* bo   = (const float*)d_in[12];

  uint2* wpk = (uint2*)d_ws;                       // 294912 B packed int8 frags
  float* wsc = (float*)((char*)d_ws + 294912);     // 9216 B row scales

  pack_weights_i8<<<9, 256, 0, stream>>>(Whr, Whz, Whn, wpk, wsc);
  gru_run<<<B_, 512, 0, stream>>>(stim, swid, mask, Win, binp,
                                  bhr, bhz, bhn, Wo, bo, wpk, wsc, (float*)d_out);
}

// Round 5
// 496.308 us; speedup vs baseline: 1.5044x; 1.0300x over previous
//
#include <hip/hip_runtime.h>
#include <stdint.h>

#define B_  256
#define T_  512
#define H_  128
#define NSW 6

typedef __bf16 bf2_t  __attribute__((ext_vector_type(2)));
typedef int    i32x4  __attribute__((ext_vector_type(4)));
typedef float  f32x4  __attribute__((ext_vector_type(4)));
typedef unsigned long ulong2_t __attribute__((ext_vector_type(2)));

// float -> bf16 round-to-nearest-even
__device__ __forceinline__ unsigned short f2bf(float f){
  unsigned u = __float_as_uint(f);
  unsigned r = u + 0x7FFFu + ((u >> 16) & 1u);
  return (unsigned short)(r >> 16);
}
__device__ __forceinline__ unsigned pack2(float a, float b){
  return (unsigned)f2bf(a) | ((unsigned)f2bf(b) << 16);
}
__device__ __forceinline__ float dot2bf(unsigned wpair, unsigned hpair, float acc){
  return __builtin_amdgcn_fdot2_f32_bf16(__builtin_bit_cast(bf2_t, wpair),
                                         __builtin_bit_cast(bf2_t, hpair), acc, false);
}
__device__ __forceinline__ void lds_barrier(){
  asm volatile("s_waitcnt lgkmcnt(0)\ns_barrier" ::: "memory");
}

// Per-row symmetric int8 quantization into MFMA *B*-fragment order (W^T).
// Tile (s, g', w) covers output rows i = 16w..16w+15 of gate g'.
// uint2 idx = ((s*24 + g'*8 + w)*4 + kc)*64 + q*16 + c holds int8 of
//   W_g'[s][i = 16w + c][k = kc*32 + q*8 + 0..7]   (byte e = k offset e)
// scales[s*384 + g'*128 + i] = rowmax / (127*127)
__global__ __launch_bounds__(256) void pack_weights_i8(const float* __restrict__ Wr,
                                                       const float* __restrict__ Wz,
                                                       const float* __restrict__ Wn,
                                                       uint2* __restrict__ dst,
                                                       float* __restrict__ scales){
  int idx = blockIdx.x * 256 + threadIdx.x;     // (s, row384)
  if (idx >= NSW * 384) return;
  int s   = idx / 384;
  int row = idx % 384;
  int gp  = row >> 7;                            // gate 0..2
  int i   = row & 127;                           // output row within gate
  const float* W = (gp == 0) ? Wr : (gp == 1) ? Wz : Wn;
  const float* src = W + (size_t)s * (H_*H_) + (size_t)i * H_;
  float amax = 0.f;
  for (int j = 0; j < H_; ++j) amax = fmaxf(amax, fabsf(src[j]));
  amax = fmaxf(amax, 1e-20f);
  float inv = 127.f / amax;
  scales[idx] = amax / 16129.f;                 // amax / 127^2
  int w = i >> 4, c = i & 15;
  for (int kc = 0; kc < 4; ++kc){
    for (int q = 0; q < 4; ++q){
      unsigned b0 = 0, b1 = 0;
      for (int e = 0; e < 8; ++e){
        int k = kc * 32 + q * 8 + e;
        int v = (int)rintf(src[k] * inv);
        v = v > 127 ? 127 : (v < -127 ? -127 : v);
        unsigned bv = (unsigned)(v & 0xFF);
        if (e < 4) b0 |= bv << (8 * e);
        else       b1 |= bv << (8 * (e - 4));
      }
      dst[((size_t)((s * 24 + gp * 8 + w) * 4 + kc)) * 64 + q * 16 + c] = make_uint2(b0, b1);
    }
  }
}

// 512 threads = 8 waves. Transposed MFMA: A = h (row 0 only), B = W^T.
// Wave w owns h rows 16w..16w+15 for all three gates; pointwise fully
// in-register on lanes L<16. ONE barrier per step.
// Round-5 deltas: v_rcp instead of fp32 div (x3); merged {bf16 mask | sid}
// u32 read once per step; h int8 stored PERMUTED so each colv lane reads its
// four 8B A-chunks as two contiguous b128 loads; scale/bias pairs reloaded
// only when sid changes (prefetched in the prior step's shadow).
__global__ __launch_bounds__(512, 2) void gru_run(const float* __restrict__ stim,
    const int*   __restrict__ swid,  const float* __restrict__ mask,
    const float* __restrict__ Win,   const float* __restrict__ binp,
    const float* __restrict__ b_hr,  const float* __restrict__ b_hz, const float* __restrict__ b_hn,
    const float* __restrict__ Wo,    const float* __restrict__ bo,
    const uint2* __restrict__ Wpk,   const float* __restrict__ Wsc,
    float* __restrict__ out)
{
  const int b   = blockIdx.x;
  const int tid = threadIdx.x;
  const int w   = tid >> 6;          // 0..7
  const int L   = tid & 63;

  __shared__ uint4          s_stim2[T_];        // 8 KB  bf16 stim pairs
  __shared__ unsigned       s_sm[T_];           // 2 KB  {bf16 mask <<16 | sid}
  __shared__ __align__(16) float2 s_sb[NSW*384];   // 18 KB {scale, bias} per (s,row384)
  __shared__ __align__(16) char   s_hb8[2][192];   // permuted int8 h slots; [128..192) zero
  __shared__ __align__(16) float  s_hf[2][H_];     // f32 h slots (output projection)

  // ---- init LDS ----
  for (int k = tid; k < T_; k += 512){
    const float* sp = stim + (size_t)b * T_ * 8 + (size_t)k * 8;
    uint4 o;
    o.x = pack2(sp[0], sp[1]); o.y = pack2(sp[2], sp[3]);
    o.z = pack2(sp[4], sp[5]); o.w = pack2(sp[6], sp[7]);
    s_stim2[k] = o;
    int ss = swid[(size_t)b * T_ + k];
    ss = ss < 0 ? 0 : (ss > NSW - 1 ? NSW - 1 : ss);
    s_sm[k] = ((unsigned)f2bf(mask[(size_t)b * T_ + k]) << 16) | (unsigned)ss;
  }
  for (int k = tid; k < NSW * 384; k += 512){
    int s = k / 384; int row = k % 384;
    int gp = row >> 7; int i = row & 127;
    const float* bp = (gp == 0) ? b_hr : (gp == 1) ? b_hz : b_hn;
    s_sb[k] = make_float2(Wsc[k], bp[s * H_ + i]);
  }
  if (tid < 96) ((int*)s_hb8)[tid] = 0;         // zero both int8 slots incl. pad

  // in-lane x-projection weights: lane l<16 of wave w owns rows gp*128+16w+l
  unsigned winp[3][4] = {{0,0,0,0},{0,0,0,0},{0,0,0,0}};
  float binr[3] = {0.f, 0.f, 0.f};
  if (L < 16){
    #pragma unroll
    for (int gp = 0; gp < 3; ++gp){
      int row = gp * 128 + 16 * w + L;
      #pragma unroll
      for (int e = 0; e < 4; ++e)
        winp[gp][e] = pack2(Win[(size_t)row * 8 + 2*e], Win[(size_t)row * 8 + 2*e + 1]);
      binr[gp] = binp[row];
    }
  }

  // output projection: waves 2 (logit 0) and 3 (logit 1)
  float wo_a = 0.f, wo_b = 0.f, bo_r = 0.f;
  const int kk = w & 1;
  const bool ow = (w == 2) || (w == 3);
  if (ow){
    wo_a = Wo[kk * H_ + L];
    wo_b = Wo[kk * H_ + 64 + L];
    bo_r = bo[kk];
  }

  const bool colv = (L & 15) == 0;
  const int  quad = L >> 4;
  float* outp = out + (size_t)b * T_ * 2;

  // A-frag read base within a slot: colv lane quad q reads 32 contiguous bytes
  // at q*32 (two b128); non-colv lanes read the zero pad at [128,160).
  const int obase = colv ? (quad * 32) : 128;
  // permuted write position for h row i = 16w + L (L<16):
  //   i = kc*32 + q*8 + e  ->  pos = q*32 + kc*8 + e
  const int hi_  = 16 * w + (L & 15);
  const int hwpos = ((hi_ >> 3) & 3) * 32 + ((hi_ >> 5) << 3) + (hi_ & 7);

  // ---- preload ALL 6 switch-sets' B fragments (W^T) into registers/AGPRs.
  //      volatile: cannot be sunk into the loop or rematerialized. 144 regs.
  uint2 Bf[6][12];
  #pragma unroll
  for (int s = 0; s < 6; ++s){
    #pragma unroll
    for (int gp = 0; gp < 3; ++gp){
      const volatile unsigned* vp =
        (const volatile unsigned*)(Wpk + ((size_t)((s * 24 + gp * 8 + w) * 4)) * 64 + L);
      #pragma unroll
      for (int kc = 0; kc < 4; ++kc){
        Bf[s][gp*4+kc].x = vp[2 * (kc * 64)];
        Bf[s][gp*4+kc].y = vp[2 * (kc * 64) + 1];
      }
    }
  }

  __syncthreads();

  // ---- loop-carried state: sc, mt, scale/bias pairs for current sc, h ----
  unsigned sm0 = s_sm[0];
  int   sc = __builtin_amdgcn_readfirstlane((int)(sm0 & 0xFFFFu));
  float mt = __uint_as_float(sm0 & 0xFFFF0000u);
  float2 sb_r, sb_z, sb_n;
  {
    int base = sc * 384 + 16 * w + (L & 15);
    sb_r = s_sb[base];
    sb_z = s_sb[base + 128];
    sb_n = s_sb[base + 256];
  }
  float hprev = 0.f;                 // lane l<16 of wave w: h row 16w+l

#define MFMA1(BL, FR, A) __builtin_amdgcn_mfma_i32_16x16x32_i8( \
        (BL), __builtin_bit_cast(long, (FR)), (A), 0, 0, 0)
#define MM(S)                                                                  \
    { i32x4 a;                                                                 \
      a = (i32x4){0,0,0,0};                                                    \
      a = MFMA1(bl0, Bf[S][0], a);  a = MFMA1(bl1, Bf[S][1], a);               \
      a = MFMA1(bl2, Bf[S][2], a);  a = MFMA1(bl3, Bf[S][3], a);  ac0 = a;     \
      a = (i32x4){0,0,0,0};                                                    \
      a = MFMA1(bl0, Bf[S][4], a);  a = MFMA1(bl1, Bf[S][5], a);               \
      a = MFMA1(bl2, Bf[S][6], a);  a = MFMA1(bl3, Bf[S][7], a);  ac1 = a;     \
      a = (i32x4){0,0,0,0};                                                    \
      a = MFMA1(bl0, Bf[S][8], a);  a = MFMA1(bl1, Bf[S][9], a);               \
      a = MFMA1(bl2, Bf[S][10], a); a = MFMA1(bl3, Bf[S][11], a); ac2 = a; }

  #pragma unroll 1
  for (int t = 0; t < T_; ++t){
    // merged {mask|sid} for t+1 (one b32); consumed at loop end
    int tn = (t + 1 < T_) ? (t + 1) : (T_ - 1);
    unsigned smn = s_sm[tn];

    // A fragments: h_{t-1} permuted int8, two contiguous b128 loads
    const char* hsrc = &s_hb8[(t + 1) & 1][0];
    ulong2_t hA = *(const ulong2_t*)(hsrc + obase);
    ulong2_t hB = *(const ulong2_t*)(hsrc + obase + 16);
    long bl0 = (long)hA.x, bl1 = (long)hA.y;
    long bl2 = (long)hB.x, bl3 = (long)hB.y;

    // x-projection for this wave's rows (independent of h; overlaps MFMA wait)
    float xr = 0.f, xz = 0.f, xn = 0.f;
    if (L < 16){
      uint4 sp = s_stim2[t];
      xr = binr[0];
      xr = dot2bf(winp[0][0], sp.x, xr); xr = dot2bf(winp[0][1], sp.y, xr);
      xr = dot2bf(winp[0][2], sp.z, xr); xr = dot2bf(winp[0][3], sp.w, xr);
      xz = binr[1];
      xz = dot2bf(winp[1][0], sp.x, xz); xz = dot2bf(winp[1][1], sp.y, xz);
      xz = dot2bf(winp[1][2], sp.z, xz); xz = dot2bf(winp[1][3], sp.w, xz);
      xn = binr[2];
      xn = dot2bf(winp[2][0], sp.x, xn); xn = dot2bf(winp[2][1], sp.y, xn);
      xn = dot2bf(winp[2][2], sp.z, xn); xn = dot2bf(winp[2][3], sp.w, xn);
    }

    // matvec: C[0][n] lands in lanes 0..15, reg .x  (A rows 1..15 are zero)
    i32x4 ac0, ac1, ac2;
    switch (sc){
      case 0: MM(0); break;
      case 1: MM(1); break;
      case 2: MM(2); break;
      case 3: MM(3); break;
      case 4: MM(4); break;
      default: MM(5); break;
    }

    // dequant + pointwise, fully in-register (lane l<16: h row 16w+l)
    if (L < 16){
      float ar = fmaf((float)ac0.x, sb_r.x, sb_r.y);
      float az = fmaf((float)ac1.x, sb_z.x, sb_z.y);
      float an = fmaf((float)ac2.x, sb_n.x, sb_n.y);
      float r = __builtin_amdgcn_rcpf(1.f + __expf(-(xr + ar)));
      float z = __builtin_amdgcn_rcpf(1.f + __expf(-(xz + az)));
      float e = __expf(2.f * fmaf(r, an, xn));     // tanh(a) = 1 - 2/(e^{2a}+1)
      float n = fmaf(-2.f, __builtin_amdgcn_rcpf(e + 1.f), 1.f);
      float hnew = fmaf(z, hprev - n, n);
      float ho   = fmaf(mt, hnew - hprev, hprev);
      hprev = ho;
      s_hf[t & 1][hi_] = ho;
      float qf = fminf(fmaxf(ho * 127.f, -127.f), 127.f);
      s_hb8[t & 1][hwpos] = (char)(int)rintf(qf);
    }

    // next-step sid/mask; reload scale/bias only if sid changed (prefetch
    // into next step's shadow; reads drain at the barrier)
    int   sidn = __builtin_amdgcn_readfirstlane((int)(smn & 0xFFFFu));
    float mtn  = __uint_as_float(smn & 0xFFFF0000u);
    if (sidn != sc){
      int base = sidn * 384 + 16 * w + (L & 15);
      sb_r = s_sb[base];
      sb_z = s_sb[base + 128];
      sb_n = s_sb[base + 256];
    }

    lds_barrier();   // the ONLY barrier: h_t (int8 + f32) visible

    // output projection (off the h critical path; overlaps next step top)
    if (ow){
      const float* hf = s_hf[t & 1];
      float p = wo_a * hf[L] + wo_b * hf[64 + L];
      p += __shfl_down(p, 32); p += __shfl_down(p, 16); p += __shfl_down(p, 8);
      p += __shfl_down(p, 4);  p += __shfl_down(p, 2);  p += __shfl_down(p, 1);
      if (L == 0) outp[t * 2 + kk] = p + bo_r;
    }

    sc = sidn;
    mt = mtn;
  }
#undef MM
#undef MFMA1
}

extern "C" void kernel_launch(void* const* d_in, const int* in_sizes, int n_in,
                              void* d_out, int out_size, void* d_ws, size_t ws_size,
                              hipStream_t stream) {
  const float* stim = (const float*)d_in[0];
  const int*   swid = (const int*)  d_in[1];
  const float* mask = (const float*)d_in[2];
  const float* Win  = (const float*)d_in[3];
  const float* binp = (const float*)d_in[4];
  const float* Whr  = (const float*)d_in[5];
  const float* Whz  = (const float*)d_in[6];
  const float* Whn  = (const float*)d_in[7];
  const float* bhr  = (const float*)d_in[8];
  const float* bhz  = (const float*)d_in[9];
  const float* bhn  = (const float*)d_in[10];
  const float* Wo   = (const float*)d_in[11];
  const float* bo   = (const float*)d_in[12];

  uint2* wpk = (uint2*)d_ws;                       // 294912 B packed int8 frags
  float* wsc = (float*)((char*)d_ws + 294912);     // 9216 B row scales

  pack_weights_i8<<<9, 256, 0, stream>>>(Whr, Whz, Whn, wpk, wsc);
  gru_run<<<B_, 512, 0, stream>>>(stim, swid, mask, Win, binp,
                                  bhr, bhz, bhn, Wo, bo, wpk, wsc, (float*)d_out);
}

// Round 6
// 434.522 us; speedup vs baseline: 1.7183x; 1.1422x over previous
//
#include <hip/hip_runtime.h>
#include <stdint.h>

#define B_  256
#define T_  512
#define H_  128
#define NSW 6

typedef __bf16 bf2_t  __attribute__((ext_vector_type(2)));
typedef int    i32x4  __attribute__((ext_vector_type(4)));
typedef float  f32x4  __attribute__((ext_vector_type(4)));
typedef unsigned long ulong2_t __attribute__((ext_vector_type(2)));

// float -> bf16 round-to-nearest-even
__device__ __forceinline__ unsigned short f2bf(float f){
  unsigned u = __float_as_uint(f);
  unsigned r = u + 0x7FFFu + ((u >> 16) & 1u);
  return (unsigned short)(r >> 16);
}
__device__ __forceinline__ unsigned pack2(float a, float b){
  return (unsigned)f2bf(a) | ((unsigned)f2bf(b) << 16);
}
__device__ __forceinline__ float dot2bf(unsigned wpair, unsigned hpair, float acc){
  return __builtin_amdgcn_fdot2_f32_bf16(__builtin_bit_cast(bf2_t, wpair),
                                         __builtin_bit_cast(bf2_t, hpair), acc, false);
}
__device__ __forceinline__ void lds_barrier(){
  asm volatile("s_waitcnt lgkmcnt(0)\ns_barrier" ::: "memory");
}

// Per-row symmetric int8 quantization into MFMA *B*-fragment order (W^T).
// Tile (s, g', w) covers output rows i = 16w..16w+15 of gate g'.
// uint2 idx = ((s*24 + g'*8 + w)*4 + kc)*64 + q*16 + c holds int8 of
//   W_g'[s][i = 16w + c][k = kc*32 + q*8 + 0..7]   (byte e = k offset e)
// scales[s*384 + g'*128 + i] = rowmax / (127*127)
__global__ __launch_bounds__(256) void pack_weights_i8(const float* __restrict__ Wr,
                                                       const float* __restrict__ Wz,
                                                       const float* __restrict__ Wn,
                                                       uint2* __restrict__ dst,
                                                       float* __restrict__ scales){
  int idx = blockIdx.x * 256 + threadIdx.x;     // (s, row384)
  if (idx >= NSW * 384) return;
  int s   = idx / 384;
  int row = idx % 384;
  int gp  = row >> 7;                            // gate 0..2
  int i   = row & 127;                           // output row within gate
  const float* W = (gp == 0) ? Wr : (gp == 1) ? Wz : Wn;
  const float* src = W + (size_t)s * (H_*H_) + (size_t)i * H_;
  float amax = 0.f;
  for (int j = 0; j < H_; ++j) amax = fmaxf(amax, fabsf(src[j]));
  amax = fmaxf(amax, 1e-20f);
  float inv = 127.f / amax;
  scales[idx] = amax / 16129.f;                 // amax / 127^2
  int w = i >> 4, c = i & 15;
  for (int kc = 0; kc < 4; ++kc){
    for (int q = 0; q < 4; ++q){
      unsigned b0 = 0, b1 = 0;
      for (int e = 0; e < 8; ++e){
        int k = kc * 32 + q * 8 + e;
        int v = (int)rintf(src[k] * inv);
        v = v > 127 ? 127 : (v < -127 ? -127 : v);
        unsigned bv = (unsigned)(v & 0xFF);
        if (e < 4) b0 |= bv << (8 * e);
        else       b1 |= bv << (8 * (e - 4));
      }
      dst[((size_t)((s * 24 + gp * 8 + w) * 4 + kc)) * 64 + q * 16 + c] = make_uint2(b0, b1);
    }
  }
}

// 512 threads = 8 waves. Transposed MFMA: A = h (row 0 only), B = W^T.
// Round-6 deltas:
//  - x-projection precomputed per 32-step chunk into s_xt (boundary block);
//    in-loop it is ONE b128 read.
//  - output projection BATCHED: per step each producing lane writes a b64
//    {wo0*ho, wo1*ho} partial; chunk boundary tree-reduces 32x128 partials
//    with all 512 threads and stores 32 float2. No per-step straggler tail.
//  - sid/mask via v_readlane from a 64-step register vector (zero DS/step).
//  - scale+bias as two b128 reads on sid-change.
//  - MFMA chains split 2+2 with integer .x adds (half the dependent latency).
__global__ __launch_bounds__(512, 2) void gru_run(const float* __restrict__ stim,
    const int*   __restrict__ swid,  const float* __restrict__ mask,
    const float* __restrict__ Win,   const float* __restrict__ binp,
    const float* __restrict__ b_hr,  const float* __restrict__ b_hz, const float* __restrict__ b_hn,
    const float* __restrict__ Wo,    const float* __restrict__ bo,
    const uint2* __restrict__ Wpk,   const float* __restrict__ Wsc,
    float* __restrict__ out)
{
  const int b   = blockIdx.x;
  const int tid = threadIdx.x;
  const int w   = tid >> 6;          // 0..7
  const int L   = tid & 63;

  __shared__ unsigned       s_sm[T_];               // 2 KB   {bf16 mask <<16 | sid}
  __shared__ __align__(16) f32x4  s_sclb[NSW][H_][2]; // 24 KB  [s][hi]{scales},{biases}
  __shared__ __align__(16) f32x4  s_xt[32][H_];       // 64 KB  x-projection chunk
  __shared__ __align__(16) float2 s_po[32][H_];       // 32 KB  output partials
  __shared__ __align__(16) char   s_hb8[2][192];      // permuted int8 h; [128..192) zero

  // ---- init LDS ----
  for (int k = tid; k < T_; k += 512){
    int ss = swid[(size_t)b * T_ + k];
    ss = ss < 0 ? 0 : (ss > NSW - 1 ? NSW - 1 : ss);
    s_sm[k] = ((unsigned)f2bf(mask[(size_t)b * T_ + k]) << 16) | (unsigned)ss;
  }
  for (int k = tid; k < NSW * H_; k += 512){
    int s = k >> 7, i = k & 127;
    s_sclb[s][i][0] = (f32x4){Wsc[s*384 + i], Wsc[s*384 + 128 + i], Wsc[s*384 + 256 + i], 0.f};
    s_sclb[s][i][1] = (f32x4){b_hr[s*H_ + i], b_hz[s*H_ + i], b_hn[s*H_ + i], 0.f};
  }
  if (tid < 96) ((int*)s_hb8)[tid] = 0;         // zero both int8 slots incl. pad

  // pre-phase x-projection weights: thread handles row hi_p for all 3 gates
  const int hi_p = tid & 127;
  const int tq   = tid >> 7;                     // 0..3: covers t-offsets tq*8..tq*8+7
  unsigned winp[3][4];
  float    binr[3];
  #pragma unroll
  for (int gp = 0; gp < 3; ++gp){
    int row = gp * 128 + hi_p;
    #pragma unroll
    for (int e = 0; e < 4; ++e)
      winp[gp][e] = pack2(Win[(size_t)row * 8 + 2*e], Win[(size_t)row * 8 + 2*e + 1]);
    binr[gp] = binp[row];
  }

  const bool colv = (L & 15) == 0;
  const int  quad = L >> 4;
  const int  hi_  = 16 * w + (L & 15);
  float* outp = out + (size_t)b * T_ * 2;
  const float bo0 = bo[0], bo1 = bo[1];
  float wo0r = 0.f, wo1r = 0.f;
  if (L < 16){ wo0r = Wo[hi_]; wo1r = Wo[H_ + hi_]; }

  // A-frag read base within a slot (colv lane quad q: 32 contiguous bytes)
  const int obase = colv ? (quad * 32) : 128;
  // permuted write position for h row hi_: i = kc*32 + q*8 + e -> q*32 + kc*8 + e
  const int hwpos = ((hi_ >> 3) & 3) * 32 + ((hi_ >> 5) << 3) + (hi_ & 7);

  // ---- preload ALL 6 switch-sets' B fragments (W^T). volatile: cannot be
  //      sunk into the loop or rematerialized. 144 regs.
  uint2 Bf[6][12];
  #pragma unroll
  for (int s = 0; s < 6; ++s){
    #pragma unroll
    for (int gp = 0; gp < 3; ++gp){
      const volatile unsigned* vp =
        (const volatile unsigned*)(Wpk + ((size_t)((s * 24 + gp * 8 + w) * 4)) * 64 + L);
      #pragma unroll
      for (int kc = 0; kc < 4; ++kc){
        Bf[s][gp*4+kc].x = vp[2 * (kc * 64)];
        Bf[s][gp*4+kc].y = vp[2 * (kc * 64) + 1];
      }
    }
  }

  __syncthreads();

  // loop-carried: scale/bias vectors for the current sid, h, sm register vector
  int sc0i = __builtin_amdgcn_readfirstlane((int)(s_sm[0] & 0xFFFFu));
  f32x4 sclv = s_sclb[sc0i][hi_][0];
  f32x4 bsv  = s_sclb[sc0i][hi_][1];
  float hprev = 0.f;
  int   smv = 0;                                 // 64 steps of {mask|sid}, lane L = step

#define MFMA1(BL, FR, A) __builtin_amdgcn_mfma_i32_16x16x32_i8( \
        (BL), __builtin_bit_cast(long, (FR)), (A), 0, 0, 0)
#define MM(S)                                                                  \
    { i32x4 a, c; const i32x4 zz = {0,0,0,0};                                  \
      a = MFMA1(bl0, Bf[S][0], zz);  a = MFMA1(bl1, Bf[S][1], a);              \
      c = MFMA1(bl2, Bf[S][2], zz);  c = MFMA1(bl3, Bf[S][3], c);              \
      acx0 = a.x + c.x;                                                        \
      a = MFMA1(bl0, Bf[S][4], zz);  a = MFMA1(bl1, Bf[S][5], a);              \
      c = MFMA1(bl2, Bf[S][6], zz);  c = MFMA1(bl3, Bf[S][7], c);              \
      acx1 = a.x + c.x;                                                        \
      a = MFMA1(bl0, Bf[S][8], zz);  a = MFMA1(bl1, Bf[S][9], a);              \
      c = MFMA1(bl2, Bf[S][10], zz); c = MFMA1(bl3, Bf[S][11], c);             \
      acx2 = a.x + c.x; }

#define REDUCE(TBASE)                                                          \
  {                                                                            \
    int tp = tid >> 4;                                                         \
    int q  = tid & 15;                                                         \
    const f32x4* prow = (const f32x4*)&s_po[tp][0];                            \
    f32x4 a0 = prow[4*q+0], a1 = prow[4*q+1], a2 = prow[4*q+2], a3 = prow[4*q+3]; \
    f32x4 sv = (a0 + a1) + (a2 + a3);                                          \
    float p0 = sv.x + sv.z, p1 = sv.y + sv.w;                                  \
    p0 += __shfl_down(p0, 8, 16); p1 += __shfl_down(p1, 8, 16);                \
    p0 += __shfl_down(p0, 4, 16); p1 += __shfl_down(p1, 4, 16);                \
    p0 += __shfl_down(p0, 2, 16); p1 += __shfl_down(p1, 2, 16);                \
    p0 += __shfl_down(p0, 1, 16); p1 += __shfl_down(p1, 1, 16);                \
    if (q == 0)                                                                \
      *(float2*)&outp[((TBASE) + tp) * 2] = make_float2(p0 + bo0, p1 + bo1);   \
  }

  #pragma unroll 1
  for (int t = 0; t < T_; ++t){
    // ---- chunk boundary: reduce previous chunk's outputs + build x̃ chunk ----
    if ((t & 31) == 0){
      if (t > 0) REDUCE(t - 32);
      #pragma unroll
      for (int j = 0; j < 8; ++j){
        int tt = t + tq * 8 + j;
        const float* sp = stim + (size_t)b * T_ * 8 + (size_t)tt * 8;
        float4 sA = *(const float4*)(sp);
        float4 sB = *(const float4*)(sp + 4);
        unsigned p0 = pack2(sA.x, sA.y), p1 = pack2(sA.z, sA.w);
        unsigned p2 = pack2(sB.x, sB.y), p3 = pack2(sB.z, sB.w);
        f32x4 xv;
        float x0 = binr[0];
        x0 = dot2bf(winp[0][0], p0, x0); x0 = dot2bf(winp[0][1], p1, x0);
        x0 = dot2bf(winp[0][2], p2, x0); x0 = dot2bf(winp[0][3], p3, x0);
        float x1 = binr[1];
        x1 = dot2bf(winp[1][0], p0, x1); x1 = dot2bf(winp[1][1], p1, x1);
        x1 = dot2bf(winp[1][2], p2, x1); x1 = dot2bf(winp[1][3], p3, x1);
        float x2 = binr[2];
        x2 = dot2bf(winp[2][0], p0, x2); x2 = dot2bf(winp[2][1], p1, x2);
        x2 = dot2bf(winp[2][2], p2, x2); x2 = dot2bf(winp[2][3], p3, x2);
        xv.x = x0; xv.y = x1; xv.z = x2; xv.w = 0.f;
        s_xt[tq * 8 + j][hi_p] = xv;
      }
      lds_barrier();
    }
    if ((t & 63) == 0) smv = (int)s_sm[t + L];   // 64 steps of {mask|sid} into a VGPR

    // per-step uniform sid/mask via readlane (zero DS)
    int   sm_c = __builtin_amdgcn_readlane(smv, t & 63);
    int   sc   = sm_c & 0xFFFF;
    float mt   = __uint_as_float((unsigned)sm_c & 0xFFFF0000u);

    // A fragments: h_{t-1} permuted int8, two contiguous b128 loads
    const char* hsrc = &s_hb8[(t + 1) & 1][0];
    ulong2_t hA = *(const ulong2_t*)(hsrc + obase);
    ulong2_t hB = *(const ulong2_t*)(hsrc + obase + 16);
    long bl0 = (long)hA.x, bl1 = (long)hA.y;
    long bl2 = (long)hB.x, bl3 = (long)hB.y;

    // x̃ for this lane's row (issued early; latency hides under MFMA)
    f32x4 xtv = s_xt[t & 31][hi_];

    // matvec: C[0][n] lands in lanes 0..15, reg .x  (A rows 1..15 are zero)
    int acx0, acx1, acx2;
    switch (sc){
      case 0: MM(0); break;
      case 1: MM(1); break;
      case 2: MM(2); break;
      case 3: MM(3); break;
      case 4: MM(4); break;
      default: MM(5); break;
    }

    // dequant + pointwise, fully in-register (lane l<16: h row 16w+l)
    if (L < 16){
      float ar = fmaf((float)acx0, sclv.x, bsv.x);
      float az = fmaf((float)acx1, sclv.y, bsv.y);
      float an = fmaf((float)acx2, sclv.z, bsv.z);
      float r = __builtin_amdgcn_rcpf(1.f + __expf(-(xtv.x + ar)));
      float z = __builtin_amdgcn_rcpf(1.f + __expf(-(xtv.y + az)));
      float e = __expf(2.f * fmaf(r, an, xtv.z));  // tanh(a) = 1 - 2/(e^{2a}+1)
      float n = fmaf(-2.f, __builtin_amdgcn_rcpf(e + 1.f), 1.f);
      float hnew = fmaf(z, hprev - n, n);
      float ho   = fmaf(mt, hnew - hprev, hprev);
      hprev = ho;
      s_po[t & 31][hi_] = make_float2(wo0r * ho, wo1r * ho);
      float qf = fminf(fmaxf(ho * 127.f, -127.f), 127.f);
      s_hb8[t & 1][hwpos] = (char)(int)rintf(qf);
    }

    // prefetch next step's scale/bias if sid changes (drains at the barrier)
    int sidn;
    if ((t & 63) == 63){
      int tn = (t + 1 < T_) ? (t + 1) : (T_ - 1);
      sidn = __builtin_amdgcn_readfirstlane((int)(s_sm[tn] & 0xFFFFu));
    } else {
      sidn = __builtin_amdgcn_readlane(smv, (t + 1) & 63) & 0xFFFF;
    }
    if (sidn != sc){
      sclv = s_sclb[sidn][hi_][0];
      bsv  = s_sclb[sidn][hi_][1];
    }

    lds_barrier();   // the ONLY barrier: h_t visible (and boundary data stable)
  }

  // final chunk's outputs
  REDUCE(T_ - 32);
#undef REDUCE
#undef MM
#undef MFMA1
}

extern "C" void kernel_launch(void* const* d_in, const int* in_sizes, int n_in,
                              void* d_out, int out_size, void* d_ws, size_t ws_size,
                              hipStream_t stream) {
  const float* stim = (const float*)d_in[0];
  const int*   swid = (const int*)  d_in[1];
  const float* mask = (const float*)d_in[2];
  const float* Win  = (const float*)d_in[3];
  const float* binp = (const float*)d_in[4];
  const float* Whr  = (const float*)d_in[5];
  const float* Whz  = (const float*)d_in[6];
  const float* Whn  = (const float*)d_in[7];
  const float* bhr  = (const float*)d_in[8];
  const float* bhz  = (const float*)d_in[9];
  const float* bhn  = (const float*)d_in[10];
  const float* Wo   = (const float*)d_in[11];
  const float* bo   = (const float*)d_in[12];

  uint2* wpk = (uint2*)d_ws;                       // 294912 B packed int8 frags
  float* wsc = (float*)((char*)d_ws + 294912);     // 9216 B row scales

  pack_weights_i8<<<9, 256, 0, stream>>>(Whr, Whz, Whn, wpk, wsc);
  gru_run<<<B_, 512, 0, stream>>>(stim, swid, mask, Win, binp,
                                  bhr, bhz, bhn, Wo, bo, wpk, wsc, (float*)d_out);
}

// Round 7
// 382.351 us; speedup vs baseline: 1.9528x; 1.1365x over previous
//
#include <hip/hip_runtime.h>
#include <stdint.h>

#define B_  256
#define T_  512
#define H_  128
#define NSW 6

typedef __bf16 bf2_t  __attribute__((ext_vector_type(2)));
typedef int    i32x4  __attribute__((ext_vector_type(4)));
typedef float  f32x4  __attribute__((ext_vector_type(4)));

// float -> bf16 round-to-nearest-even
__device__ __forceinline__ unsigned short f2bf(float f){
  unsigned u = __float_as_uint(f);
  unsigned r = u + 0x7FFFu + ((u >> 16) & 1u);
  return (unsigned short)(r >> 16);
}
__device__ __forceinline__ unsigned pack2(float a, float b){
  return (unsigned)f2bf(a) | ((unsigned)f2bf(b) << 16);
}
__device__ __forceinline__ float dot2bf(unsigned wpair, unsigned hpair, float acc){
  return __builtin_amdgcn_fdot2_f32_bf16(__builtin_bit_cast(bf2_t, wpair),
                                         __builtin_bit_cast(bf2_t, hpair), acc, false);
}
__device__ __forceinline__ void lds_barrier(){
  asm volatile("s_waitcnt lgkmcnt(0)\ns_barrier" ::: "memory");
}

// Per-row symmetric int8 quantization into MFMA B-fragment order for
// mfma_i32_16x16x64_i8 (W^T). Tile (s, g', w) covers rows i = 16w..16w+15 of
// gate g'; half m covers k = 64m..64m+63.
// uint4 idx = ((s*24 + g'*8 + w)*2 + m)*64 + q*16 + c holds int8 of
//   W_g'[s][i = 16w + c][k = m*64 + q*16 + e]  (byte e of word e>>2)
// A-side (h) uses the same (quad,byte)<->k convention -> any HW k-permutation
// cancels. scales[s*384 + g'*128 + i] = rowmax / (127*127)
__global__ __launch_bounds__(256) void pack_weights_i8(const float* __restrict__ Wr,
                                                       const float* __restrict__ Wz,
                                                       const float* __restrict__ Wn,
                                                       uint4* __restrict__ dst,
                                                       float* __restrict__ scales){
  int idx = blockIdx.x * 256 + threadIdx.x;     // (s, row384)
  if (idx >= NSW * 384) return;
  int s   = idx / 384;
  int row = idx % 384;
  int gp  = row >> 7;                            // gate 0..2
  int i   = row & 127;                           // output row within gate
  const float* W = (gp == 0) ? Wr : (gp == 1) ? Wz : Wn;
  const float* src = W + (size_t)s * (H_*H_) + (size_t)i * H_;
  float amax = 0.f;
  for (int j = 0; j < H_; ++j) amax = fmaxf(amax, fabsf(src[j]));
  amax = fmaxf(amax, 1e-20f);
  float inv = 127.f / amax;
  scales[idx] = amax / 16129.f;                 // amax / 127^2
  int w = i >> 4, c = i & 15;
  for (int m = 0; m < 2; ++m){
    for (int q = 0; q < 4; ++q){
      unsigned bw[4] = {0, 0, 0, 0};
      for (int e = 0; e < 16; ++e){
        int k = m * 64 + q * 16 + e;
        int v = (int)rintf(src[k] * inv);
        v = v > 127 ? 127 : (v < -127 ? -127 : v);
        bw[e >> 2] |= ((unsigned)(v & 0xFF)) << (8 * (e & 3));
      }
      dst[((size_t)((s * 24 + gp * 8 + w) * 2 + m)) * 64 + q * 16 + c] =
        make_uint4(bw[0], bw[1], bw[2], bw[3]);
    }
  }
}

// 512 threads = 8 waves. Transposed MFMA: A = h (row 0 only), B = W^T.
// Round-7 deltas:
//  - mfma_i32_16x16x64_i8: 6 MFMAs/step (was 12) at 2x ops/instr -> MFMA-pipe
//    time halves; h int8 layout becomes plain LINEAR (A-frag = two contiguous
//    b128 reads at quad*16 and 64+quad*16).
//  - s_stim2 restored: stim packed to bf16 once in init; chunk boundary reads
//    LDS uint4 (no global re-read / re-pack per chunk).
//  - REDUCE bank-conflict fix: swizzled read idx q+16r, s_po rows padded to 130.
__global__ __launch_bounds__(512, 2) void gru_run(const float* __restrict__ stim,
    const int*   __restrict__ swid,  const float* __restrict__ mask,
    const float* __restrict__ Win,   const float* __restrict__ binp,
    const float* __restrict__ b_hr,  const float* __restrict__ b_hz, const float* __restrict__ b_hn,
    const float* __restrict__ Wo,    const float* __restrict__ bo,
    const uint4* __restrict__ Wpk,   const float* __restrict__ Wsc,
    float* __restrict__ out)
{
  const int b   = blockIdx.x;
  const int tid = threadIdx.x;
  const int w   = tid >> 6;          // 0..7
  const int L   = tid & 63;

  __shared__ uint4          s_stim2[T_];            // 8 KB   bf16 stim pairs
  __shared__ unsigned       s_sm[T_];               // 2 KB   {bf16 mask <<16 | sid}
  __shared__ __align__(16) f32x4  s_sclb[NSW][H_][2]; // 24 KB  [s][hi]{scales},{biases}
  __shared__ __align__(16) f32x4  s_xt[32][H_];       // 64 KB  x-projection chunk
  __shared__ __align__(16) float2 s_po[32][130];      // 32.5 KB output partials (padded)
  __shared__ __align__(16) char   s_hb8[2][192];      // linear int8 h; [128..192) zero

  // ---- init LDS ----
  for (int k = tid; k < T_; k += 512){
    const float* sp = stim + (size_t)b * T_ * 8 + (size_t)k * 8;
    uint4 o;
    o.x = pack2(sp[0], sp[1]); o.y = pack2(sp[2], sp[3]);
    o.z = pack2(sp[4], sp[5]); o.w = pack2(sp[6], sp[7]);
    s_stim2[k] = o;
    int ss = swid[(size_t)b * T_ + k];
    ss = ss < 0 ? 0 : (ss > NSW - 1 ? NSW - 1 : ss);
    s_sm[k] = ((unsigned)f2bf(mask[(size_t)b * T_ + k]) << 16) | (unsigned)ss;
  }
  for (int k = tid; k < NSW * H_; k += 512){
    int s = k >> 7, i = k & 127;
    s_sclb[s][i][0] = (f32x4){Wsc[s*384 + i], Wsc[s*384 + 128 + i], Wsc[s*384 + 256 + i], 0.f};
    s_sclb[s][i][1] = (f32x4){b_hr[s*H_ + i], b_hz[s*H_ + i], b_hn[s*H_ + i], 0.f};
  }
  if (tid < 96) ((int*)s_hb8)[tid] = 0;         // zero both int8 slots incl. pad

  // pre-phase x-projection weights: thread handles row hi_p for all 3 gates
  const int hi_p = tid & 127;
  const int tq   = tid >> 7;                     // 0..3: covers t-offsets tq*8..tq*8+7
  unsigned winp[3][4];
  float    binr[3];
  #pragma unroll
  for (int gp = 0; gp < 3; ++gp){
    int row = gp * 128 + hi_p;
    #pragma unroll
    for (int e = 0; e < 4; ++e)
      winp[gp][e] = pack2(Win[(size_t)row * 8 + 2*e], Win[(size_t)row * 8 + 2*e + 1]);
    binr[gp] = binp[row];
  }

  const bool colv = (L & 15) == 0;
  const int  quad = L >> 4;
  const int  hi_  = 16 * w + (L & 15);
  float* outp = out + (size_t)b * T_ * 2;
  const float bo0 = bo[0], bo1 = bo[1];
  float wo0r = 0.f, wo1r = 0.f;
  if (L < 16){ wo0r = Wo[hi_]; wo1r = Wo[H_ + hi_]; }

  // A-frag read offsets (linear h): colv lane quad q reads 16B at q*16 and
  // 64 + q*16; non-colv lanes read the zero pad at [128,144).
  const int obase0 = colv ? (quad * 16)      : 128;
  const int obase1 = colv ? (64 + quad * 16) : 128;

  // ---- preload ALL 6 switch-sets' B fragments (W^T). volatile: cannot be
  //      sunk into the loop or rematerialized. 6 x 6 x uint4 = 144 regs.
  uint4 Bf[6][6];
  #pragma unroll
  for (int s = 0; s < 6; ++s){
    #pragma unroll
    for (int gp = 0; gp < 3; ++gp){
      #pragma unroll
      for (int m = 0; m < 2; ++m){
        const volatile unsigned* vp =
          (const volatile unsigned*)(Wpk + ((size_t)((s * 24 + gp * 8 + w) * 2 + m)) * 64 + L);
        Bf[s][gp*2+m].x = vp[0];
        Bf[s][gp*2+m].y = vp[1];
        Bf[s][gp*2+m].z = vp[2];
        Bf[s][gp*2+m].w = vp[3];
      }
    }
  }

  __syncthreads();

  // loop-carried: scale/bias vectors for the current sid, h, sm register vector
  int sc0i = __builtin_amdgcn_readfirstlane((int)(s_sm[0] & 0xFFFFu));
  f32x4 sclv = s_sclb[sc0i][hi_][0];
  f32x4 bsv  = s_sclb[sc0i][hi_][1];
  float hprev = 0.f;
  int   smv = 0;                                 // 64 steps of {mask|sid}, lane L = step

#define MFMA64(A_, B_, C_) __builtin_amdgcn_mfma_i32_16x16x64_i8( \
    __builtin_bit_cast(i32x4, (A_)), __builtin_bit_cast(i32x4, (B_)), (C_), 0, 0, 0)
#define MM(S)                                                                  \
    { i32x4 a; const i32x4 zz = {0,0,0,0};                                     \
      a = MFMA64(blo, Bf[S][0], zz); a = MFMA64(bhi, Bf[S][1], a); acx0 = a.x; \
      a = MFMA64(blo, Bf[S][2], zz); a = MFMA64(bhi, Bf[S][3], a); acx1 = a.x; \
      a = MFMA64(blo, Bf[S][4], zz); a = MFMA64(bhi, Bf[S][5], a); acx2 = a.x; }

#define REDUCE(TBASE)                                                          \
  {                                                                            \
    int tp = tid >> 4;                                                         \
    int q  = tid & 15;                                                         \
    const f32x4* prow = (const f32x4*)&s_po[tp][0];                            \
    f32x4 a0 = prow[q], a1 = prow[q+16], a2 = prow[q+32], a3 = prow[q+48];     \
    f32x4 sv = (a0 + a1) + (a2 + a3);                                          \
    float p0 = sv.x + sv.z, p1 = sv.y + sv.w;                                  \
    p0 += __shfl_down(p0, 8, 16); p1 += __shfl_down(p1, 8, 16);                \
    p0 += __shfl_down(p0, 4, 16); p1 += __shfl_down(p1, 4, 16);                \
    p0 += __shfl_down(p0, 2, 16); p1 += __shfl_down(p1, 2, 16);                \
    p0 += __shfl_down(p0, 1, 16); p1 += __shfl_down(p1, 1, 16);                \
    if (q == 0)                                                                \
      *(float2*)&outp[((TBASE) + tp) * 2] = make_float2(p0 + bo0, p1 + bo1);   \
  }

  #pragma unroll 1
  for (int t = 0; t < T_; ++t){
    // ---- chunk boundary: reduce previous chunk's outputs + build x̃ chunk ----
    if ((t & 31) == 0){
      if (t > 0) REDUCE(t - 32);
      #pragma unroll
      for (int j = 0; j < 8; ++j){
        int tt = t + tq * 8 + j;
        uint4 sp = s_stim2[tt];
        f32x4 xv;
        float x0 = binr[0];
        x0 = dot2bf(winp[0][0], sp.x, x0); x0 = dot2bf(winp[0][1], sp.y, x0);
        x0 = dot2bf(winp[0][2], sp.z, x0); x0 = dot2bf(winp[0][3], sp.w, x0);
        float x1 = binr[1];
        x1 = dot2bf(winp[1][0], sp.x, x1); x1 = dot2bf(winp[1][1], sp.y, x1);
        x1 = dot2bf(winp[1][2], sp.z, x1); x1 = dot2bf(winp[1][3], sp.w, x1);
        float x2 = binr[2];
        x2 = dot2bf(winp[2][0], sp.x, x2); x2 = dot2bf(winp[2][1], sp.y, x2);
        x2 = dot2bf(winp[2][2], sp.z, x2); x2 = dot2bf(winp[2][3], sp.w, x2);
        xv.x = x0; xv.y = x1; xv.z = x2; xv.w = 0.f;
        s_xt[tq * 8 + j][hi_p] = xv;
      }
      lds_barrier();
    }
    if ((t & 63) == 0) smv = (int)s_sm[t + L];   // 64 steps of {mask|sid} into a VGPR

    // per-step uniform sid/mask via readlane (zero DS)
    int   sm_c = __builtin_amdgcn_readlane(smv, t & 63);
    int   sc   = sm_c & 0xFFFF;
    float mt   = __uint_as_float((unsigned)sm_c & 0xFFFF0000u);

    // A fragments: h_{t-1} linear int8, two contiguous b128 loads
    const char* hsrc = &s_hb8[(t + 1) & 1][0];
    uint4 blo = *(const uint4*)(hsrc + obase0);
    uint4 bhi = *(const uint4*)(hsrc + obase1);

    // x̃ for this lane's row (issued early; latency hides under MFMA)
    f32x4 xtv = s_xt[t & 31][hi_];

    // matvec: C[0][n] lands in lanes 0..15, reg .x  (A rows 1..15 are zero)
    int acx0, acx1, acx2;
    switch (sc){
      case 0: MM(0); break;
      case 1: MM(1); break;
      case 2: MM(2); break;
      case 3: MM(3); break;
      case 4: MM(4); break;
      default: MM(5); break;
    }

    // dequant + pointwise, fully in-register (lane l<16: h row 16w+l)
    if (L < 16){
      float ar = fmaf((float)acx0, sclv.x, bsv.x);
      float az = fmaf((float)acx1, sclv.y, bsv.y);
      float an = fmaf((float)acx2, sclv.z, bsv.z);
      float r = __builtin_amdgcn_rcpf(1.f + __expf(-(xtv.x + ar)));
      float z = __builtin_amdgcn_rcpf(1.f + __expf(-(xtv.y + az)));
      float e = __expf(2.f * fmaf(r, an, xtv.z));  // tanh(a) = 1 - 2/(e^{2a}+1)
      float n = fmaf(-2.f, __builtin_amdgcn_rcpf(e + 1.f), 1.f);
      float hnew = fmaf(z, hprev - n, n);
      float ho   = fmaf(mt, hnew - hprev, hprev);
      hprev = ho;
      s_po[t & 31][hi_] = make_float2(wo0r * ho, wo1r * ho);
      float qf = fminf(fmaxf(ho * 127.f, -127.f), 127.f);
      s_hb8[t & 1][hi_] = (char)(int)rintf(qf);
    }

    // prefetch next step's scale/bias if sid changes (drains at the barrier)
    int sidn;
    if ((t & 63) == 63){
      int tn = (t + 1 < T_) ? (t + 1) : (T_ - 1);
      sidn = __builtin_amdgcn_readfirstlane((int)(s_sm[tn] & 0xFFFFu));
    } else {
      sidn = __builtin_amdgcn_readlane(smv, (t + 1) & 63) & 0xFFFF;
    }
    if (sidn != sc){
      sclv = s_sclb[sidn][hi_][0];
      bsv  = s_sclb[sidn][hi_][1];
    }

    lds_barrier();   // the ONLY barrier: h_t visible (and boundary data stable)
  }

  // final chunk's outputs
  REDUCE(T_ - 32);
#undef REDUCE
#undef MM
#undef MFMA64
}

extern "C" void kernel_launch(void* const* d_in, const int* in_sizes, int n_in,
                              void* d_out, int out_size, void* d_ws, size_t ws_size,
                              hipStream_t stream) {
  const float* stim = (const float*)d_in[0];
  const int*   swid = (const int*)  d_in[1];
  const float* mask = (const float*)d_in[2];
  const float* Win  = (const float*)d_in[3];
  const float* binp = (const float*)d_in[4];
  const float* Whr  = (const float*)d_in[5];
  const float* Whz  = (const float*)d_in[6];
  const float* Whn  = (const float*)d_in[7];
  const float* bhr  = (const float*)d_in[8];
  const float* bhz  = (const float*)d_in[9];
  const float* bhn  = (const float*)d_in[10];
  const float* Wo   = (const float*)d_in[11];
  const float* bo   = (const float*)d_in[12];

  uint4* wpk = (uint4*)d_ws;                       // 294912 B packed int8 frags
  float* wsc = (float*)((char*)d_ws + 294912);     // 9216 B row scales

  pack_weights_i8<<<9, 256, 0, stream>>>(Whr, Whz, Whn, wpk, wsc);
  gru_run<<<B_, 512, 0, stream>>>(stim, swid, mask, Win, binp,
                                  bhr, bhz, bhn, Wo, bo, wpk, wsc, (float*)d_out);
}